// Round 15
// baseline (9856.383 us; speedup 1.0000x reference)
//
#include <hip/hip_runtime.h>

// MultiTaskLSTM: B=512, T=1024, I=64, H=256
// R15: ZERO-EXCHANGE structure. 32 blocks x 16 batch rows; each block runs
// the entire T=1024 recurrence locally (batch rows independent). No flags,
// no spins, no cooperative launch. Per wave (8/block): 8 n-tiles (4 gates x
// 2 colgrps of 16 h-cols). W sources: tiles 0,1 register-resident (AGPR),
// tiles 2..7 streamed from L2 each step with 1-2 tile lookahead (plain loads;
// opaque-pointer asm defeats LICM so compiler-managed waits stay correct).
// MFMA C-layout gives each thread all 4 gates at the same (row,col) -> gate
// combine fully in-register (no transpose). LDS = double-buffered h only.

typedef __attribute__((ext_vector_type(4))) float f32x4;
typedef __attribute__((ext_vector_type(4))) unsigned int u32x4;
typedef __attribute__((ext_vector_type(8))) short bf16x8;
typedef __attribute__((ext_vector_type(8))) unsigned short u16x8;

#define T_SZ 1024
#define I_SZ 64
#define H_SZ 256
#define KFRAGS 10
#define NTHREADS 512
#define NBLK 32

#define WT_FRAGS (64 * KFRAGS * 64)        // 40960 frags x 16B
#define WS_BIAS_OFF (WT_FRAGS * 16)

#define HST 264                             // h_lds row stride (u16)

__device__ __forceinline__ unsigned short f2bf(float f) {
    unsigned int u = __builtin_bit_cast(unsigned int, f);
    unsigned int r = (u + 0x7FFFu + ((u >> 16) & 1u)) >> 16;
    return (unsigned short)r;
}
__device__ __forceinline__ float bf2f(unsigned short s) {
    unsigned int u = ((unsigned int)s) << 16;
    return __builtin_bit_cast(float, u);
}
__device__ __forceinline__ float sigm(float x) {
    return 1.0f / (1.0f + exp2f(-1.44269504f * x));
}
__device__ __forceinline__ float tanhfast(float x) {
    float e = exp2f(2.88539008f * x);
    return 1.0f - 2.0f / (e + 1.0f);
}

// W pack: frag id = ((w*8 + t)*10 + kf); lane n = lane&15:
//   gate = t&3, cg = t>>2; gate row g = gate*256 + w*32 + cg*16 + n
//   k = kf*32 + (lane>>4)*8 + j  (k<256 -> W_hh, else W_ih)
__global__ void prep_kernel(const float* __restrict__ W_ih,
                            const float* __restrict__ W_hh,
                            const float* __restrict__ b_ih,
                            const float* __restrict__ b_hh,
                            unsigned short* __restrict__ Wt,
                            float* __restrict__ bias) {
    int gid = blockIdx.x * blockDim.x + threadIdx.x;
    if (gid < WT_FRAGS) {
        int lane = gid & 63;
        int rest = gid >> 6;              // 0..639
        int kf = rest % KFRAGS;
        int tileid = rest / KFRAGS;       // 0..63
        int w  = tileid >> 3;
        int tt = tileid & 7;
        int g = (tt & 3) * 256 + w * 32 + (tt >> 2) * 16 + (lane & 15);
        int k0 = kf * 32 + (lane >> 4) * 8;
        u16x8 v;
        #pragma unroll
        for (int j = 0; j < 8; ++j) {
            int k = k0 + j;
            float wv = (k < H_SZ) ? W_hh[g * H_SZ + k]
                                  : W_ih[g * I_SZ + (k - H_SZ)];
            v[j] = f2bf(wv);
        }
        ((u16x8*)Wt)[gid] = v;
    } else if (gid < WT_FRAGS + 1024) {
        int j = gid - WT_FRAGS;
        bias[j] = b_ih[j] + b_hh[j];
    }
}

#define MFMA16(A, B, C) __builtin_amdgcn_mfma_f32_16x16x32_bf16(A, B, C, 0, 0, 0)

#define TILE10(ACC, B) do { \
    ACC = MFMA16(ah[0], B[0], ACC); \
    ACC = MFMA16(ah[1], B[1], ACC); \
    ACC = MFMA16(ah[2], B[2], ACC); \
    ACC = MFMA16(ah[3], B[3], ACC); \
    ACC = MFMA16(ah[4], B[4], ACC); \
    ACC = MFMA16(ah[5], B[5], ACC); \
    ACC = MFMA16(ah[6], B[6], ACC); \
    ACC = MFMA16(ah[7], B[7], ACC); \
    ACC = MFMA16(xf0,   B[8], ACC); \
    ACC = MFMA16(xf1,   B[9], ACC); } while (0)

// stream a full tile's 10 frags from the opaque base (defeats LICM)
#define LOADT(DST, T_) do { \
    _Pragma("unroll") \
    for (int kf_ = 0; kf_ < KFRAGS; ++kf_) \
        DST[kf_] = *(const bf16x8*)(Wts + \
            ((size_t)((wave * 8 + (T_)) * KFRAGS + kf_) * 64 + lane) * 8); \
    } while (0)

// elementwise for one colgrp: gates in-register (same thread holds i,f,g,o
// at (row rb+q, col n)); pack bf16 pairs via shfl_xor(1); write to hw.
#define EW(AI, AF, AG, AO, C, BI, BF, BG, BO, CG) do { \
    _Pragma("unroll") \
    for (int q_ = 0; q_ < 4; ++q_) { \
        float gi = AI[q_] + BI, gf = AF[q_] + BF; \
        float gg_ = AG[q_] + BG, go = AO[q_] + BO; \
        float ii = sigm(gi), ff = sigm(gf); \
        float gv = tanhfast(gg_), oo = sigm(go); \
        float cc_ = ff * C[q_] + ii * gv; C[q_] = cc_; \
        float hh = oo * tanhfast(cc_); \
        unsigned hu = (unsigned)f2bf(hh); \
        unsigned pr = (unsigned)__shfl_xor((int)hu, 1); \
        if (!(lane & 1)) { \
            *(unsigned*)&hw[(rb + q_) * HST + wave * 32 + (CG) * 16 + n] = \
                hu | (pr << 16); \
        } \
    } } while (0)

__global__ __launch_bounds__(NTHREADS)
void lstm_kernel(const float* __restrict__ x,
                 const unsigned short* __restrict__ Wt,
                 const float* __restrict__ bias,
                 const float* __restrict__ W_dir, const float* __restrict__ b_dir,
                 const float* __restrict__ W_q,   const float* __restrict__ b_q,
                 const float* __restrict__ W_rr,  const float* __restrict__ b_rr,
                 const float* __restrict__ W_sl,  const float* __restrict__ b_sl,
                 float* __restrict__ out)
{
    __shared__ __align__(16) unsigned short h_lds[2][16 * HST];  // 16.9 KB

    const int tid  = threadIdx.x;
    const int lane = tid & 63;
    const int wave = tid >> 6;
    const int b0   = blockIdx.x * 16;
    const int n    = lane & 15;        // B col / A row / D col
    const int hg   = lane >> 4;        // 0..3
    const int rb   = hg * 4;           // D row base

    // ---- register-resident W: tiles 0,1 (compiler -> AGPR) ----
    bf16x8 wr0[KFRAGS], wr1[KFRAGS];
    #pragma unroll
    for (int kf = 0; kf < KFRAGS; ++kf) {
        wr0[kf] = *(const bf16x8*)(Wt +
            ((size_t)((wave * 8 + 0) * KFRAGS + kf) * 64 + lane) * 8);
        wr1[kf] = *(const bf16x8*)(Wt +
            ((size_t)((wave * 8 + 1) * KFRAGS + kf) * 64 + lane) * 8);
    }

    // ---- per-thread biases (col per colgrp) ----
    const int col0 = wave * 32 + n;
    const int col1 = wave * 32 + 16 + n;
    const float bI0 = bias[col0],       bF0 = bias[256 + col0];
    const float bG0 = bias[512 + col0], bO0 = bias[768 + col0];
    const float bI1 = bias[col1],       bF1 = bias[256 + col1];
    const float bG1 = bias[512 + col1], bO1 = bias[768 + col1];

    // ---- zero h buffer 0 (h_0 = 0) ----
    {
        unsigned int* hz = (unsigned int*)&h_lds[0][0];
        for (int i = tid; i < (16 * HST) / 2; i += NTHREADS) hz[i] = 0u;
    }

    float c0[4] = {0.f, 0.f, 0.f, 0.f};
    float c1[4] = {0.f, 0.f, 0.f, 0.f};

    // ---- x_0 ----
    const float* xbase = x + (size_t)(b0 + n) * (T_SZ * I_SZ) + hg * 8;
    f32x4 xa = *(const f32x4*)xbase;
    f32x4 xb = *(const f32x4*)(xbase + 4);
    f32x4 xc = *(const f32x4*)(xbase + 32);
    f32x4 xd = *(const f32x4*)(xbase + 36);
    bf16x8 xf0, xf1;
    {
        unsigned p0, p1, p2, p3, p4, p5, p6, p7;
        asm("v_cvt_pk_bf16_f32 %0, %1, %2" : "=v"(p0) : "v"(xa[0]), "v"(xa[1]));
        asm("v_cvt_pk_bf16_f32 %0, %1, %2" : "=v"(p1) : "v"(xa[2]), "v"(xa[3]));
        asm("v_cvt_pk_bf16_f32 %0, %1, %2" : "=v"(p2) : "v"(xb[0]), "v"(xb[1]));
        asm("v_cvt_pk_bf16_f32 %0, %1, %2" : "=v"(p3) : "v"(xb[2]), "v"(xb[3]));
        asm("v_cvt_pk_bf16_f32 %0, %1, %2" : "=v"(p4) : "v"(xc[0]), "v"(xc[1]));
        asm("v_cvt_pk_bf16_f32 %0, %1, %2" : "=v"(p5) : "v"(xc[2]), "v"(xc[3]));
        asm("v_cvt_pk_bf16_f32 %0, %1, %2" : "=v"(p6) : "v"(xd[0]), "v"(xd[1]));
        asm("v_cvt_pk_bf16_f32 %0, %1, %2" : "=v"(p7) : "v"(xd[2]), "v"(xd[3]));
        xf0 = __builtin_bit_cast(bf16x8, (u32x4){p0, p1, p2, p3});
        xf1 = __builtin_bit_cast(bf16x8, (u32x4){p4, p5, p6, p7});
    }

    // opaque W base for streamed loads (prevents loop-invariant hoisting)
    unsigned long long wtsa = (unsigned long long)Wt;

    __syncthreads();

    for (int t = 0; t < T_SZ; ++t) {
        asm("" : "+s"(wtsa));
        const unsigned short* Wts = (const unsigned short*)wtsa;
        const unsigned short* hb = h_lds[t & 1];
        unsigned short* hw = h_lds[(t + 1) & 1];

        // ---- A-frags (h) from LDS ----
        bf16x8 ah[8];
        #pragma unroll
        for (int kf = 0; kf < 8; ++kf)
            ah[kf] = *(const bf16x8*)(hb + n * HST + kf * 32 + hg * 8);

        // ---- issue streamed tiles 2,3; compute resident 0,1 ----
        bf16x8 s2[KFRAGS]; LOADT(s2, 2);
        bf16x8 s3[KFRAGS]; LOADT(s3, 3);
        f32x4 acc0 = {0.f, 0.f, 0.f, 0.f};
        f32x4 acc1 = {0.f, 0.f, 0.f, 0.f};
        f32x4 acc2 = {0.f, 0.f, 0.f, 0.f};
        f32x4 acc3 = {0.f, 0.f, 0.f, 0.f};
        TILE10(acc0, wr0);
        TILE10(acc1, wr1);
        TILE10(acc2, s2);
        bf16x8 s4[KFRAGS]; LOADT(s4, 4);
        TILE10(acc3, s3);

        // ---- elementwise colgrp 0 (tiles 0..3 = gates i,f,g,o) ----
        EW(acc0, acc1, acc2, acc3, c0, bI0, bF0, bG0, bO0, 0);

        bf16x8 s5[KFRAGS]; LOADT(s5, 5);
        f32x4 acc4 = {0.f, 0.f, 0.f, 0.f};
        f32x4 acc5 = {0.f, 0.f, 0.f, 0.f};
        f32x4 acc6 = {0.f, 0.f, 0.f, 0.f};
        f32x4 acc7 = {0.f, 0.f, 0.f, 0.f};
        TILE10(acc4, s4);
        bf16x8 s6[KFRAGS]; LOADT(s6, 6);
        TILE10(acc5, s5);
        bf16x8 s7[KFRAGS]; LOADT(s7, 7);
        TILE10(acc6, s6);

        // ---- x_{t+1} prefetch (plain loads; used after acc7) ----
        const float* xp = xbase + (size_t)((t + 1 < T_SZ) ? t + 1 : t) * I_SZ;
        xa = *(const f32x4*)xp;
        xb = *(const f32x4*)(xp + 4);
        xc = *(const f32x4*)(xp + 32);
        xd = *(const f32x4*)(xp + 36);

        TILE10(acc7, s7);

        // ---- elementwise colgrp 1 (tiles 4..7) ----
        EW(acc4, acc5, acc6, acc7, c1, bI1, bF1, bG1, bO1, 1);

        // ---- convert x for next step ----
        {
            unsigned p0, p1, p2, p3, p4, p5, p6, p7;
            asm("v_cvt_pk_bf16_f32 %0, %1, %2" : "=v"(p0) : "v"(xa[0]), "v"(xa[1]));
            asm("v_cvt_pk_bf16_f32 %0, %1, %2" : "=v"(p1) : "v"(xa[2]), "v"(xa[3]));
            asm("v_cvt_pk_bf16_f32 %0, %1, %2" : "=v"(p2) : "v"(xb[0]), "v"(xb[1]));
            asm("v_cvt_pk_bf16_f32 %0, %1, %2" : "=v"(p3) : "v"(xb[2]), "v"(xb[3]));
            asm("v_cvt_pk_bf16_f32 %0, %1, %2" : "=v"(p4) : "v"(xc[0]), "v"(xc[1]));
            asm("v_cvt_pk_bf16_f32 %0, %1, %2" : "=v"(p5) : "v"(xc[2]), "v"(xc[3]));
            asm("v_cvt_pk_bf16_f32 %0, %1, %2" : "=v"(p6) : "v"(xd[0]), "v"(xd[1]));
            asm("v_cvt_pk_bf16_f32 %0, %1, %2" : "=v"(p7) : "v"(xd[2]), "v"(xd[3]));
            xf0 = __builtin_bit_cast(bf16x8, (u32x4){p0, p1, p2, p3});
            xf1 = __builtin_bit_cast(bf16x8, (u32x4){p4, p5, p6, p7});
        }

        __syncthreads();   // h(t+1) complete + visible before next step reads
    }

    // ---- heads: block-local (h_T in buffer 0 since T even) ----
    if (tid < 16 * 8) {
        int r = tid >> 3, cc = tid & 7;
        const float* wrow;
        float bb;
        if (cc == 0)      { wrow = W_dir;                 bb = b_dir[0]; }
        else if (cc <= 5) { wrow = W_q + (cc - 1) * H_SZ; bb = b_q[cc - 1]; }
        else if (cc == 6) { wrow = W_rr;                  bb = b_rr[0]; }
        else              { wrow = W_sl;                  bb = b_sl[0]; }
        float s = bb;
        for (int k = 0; k < H_SZ; ++k)
            s += bf2f(h_lds[0][r * HST + k]) * wrow[k];
        float v = (cc == 0) ? tanhfast(s) : (cc == 7) ? sigm(s) : s;
        out[(b0 + r) * 8 + cc] = v;
    }
}

extern "C" void kernel_launch(void* const* d_in, const int* in_sizes, int n_in,
                              void* d_out, int out_size, void* d_ws, size_t ws_size,
                              hipStream_t stream) {
    const float* x     = (const float*)d_in[0];
    const float* W_ih  = (const float*)d_in[1];
    const float* W_hh  = (const float*)d_in[2];
    const float* b_ih  = (const float*)d_in[3];
    const float* b_hh  = (const float*)d_in[4];
    const float* W_dir = (const float*)d_in[5];
    const float* b_dir = (const float*)d_in[6];
    const float* W_q   = (const float*)d_in[7];
    const float* b_q   = (const float*)d_in[8];
    const float* W_rr  = (const float*)d_in[9];
    const float* b_rr  = (const float*)d_in[10];
    const float* W_sl  = (const float*)d_in[11];
    const float* b_sl  = (const float*)d_in[12];

    unsigned short* Wt = (unsigned short*)d_ws;
    float* bias        = (float*)((char*)d_ws + WS_BIAS_OFF);
    float* outp        = (float*)d_out;

    // 40960 frags + 1024 bias = 41984 = 164 * 256
    prep_kernel<<<164, 256, 0, stream>>>(W_ih, W_hh, b_ih, b_hh, Wt, bias);
    lstm_kernel<<<NBLK, NTHREADS, 0, stream>>>(x, Wt, bias,
                                               W_dir, b_dir, W_q, b_q,
                                               W_rr, b_rr, W_sl, b_sl, outp);
}